// Round 3
// baseline (1103.450 us; speedup 1.0000x reference)
//
#include <hip/hip_runtime.h>
#include <math.h>
#include <stdint.h>

// Problem constants
#define BB   32     // batch
#define NN   2048   // input capsules
#define KK   16     // input dim
#define CC   32     // output capsules
#define DD   32     // capsule dim
#define NCOL 1024   // CC*DD
#define NPB  8      // n per block -> 256 blocks (1/CU)
#define OSZ  (BB * NCOL)          // 32768 floats = one full o/partial image
#define NSLICE 8                  // reduce tree fan-in stage 1: 256 -> 8

// async global->LDS, 16 B per lane. LDS dest = wave-uniform base + lane*16.
// uintptr_t round-trip: generic LDS addr low 32 bits are the LDS offset.
__device__ __forceinline__ void dma16(const float* g, float* l) {
    __builtin_amdgcn_global_load_lds(
        (const __attribute__((address_space(1))) void*)(uintptr_t)g,
        (__attribute__((address_space(3))) void*)(uintptr_t)l,
        16, 0, 0);
}

// One routing iteration, fused. Per n:
//   U[b,col] = sum_k u[b,n,k] * W[n,k,col]; logit[b,c] = <U, onorm>;
//   softmax over caps; opart += c*U.
// W tile (64 KB) staged to LDS in 4 double-buffered 16 KB quarters via
// global_load_lds, so each W byte crosses L2 ONCE per block (round-2 counters
// showed 8x redundant reads -> 2.2x W HBM re-fetch + L2 BW floor).
// Thread map: bg=tid>>7 (4 b's), cq=tid&127 -> cols c0=cq*4 and c0+512,
// i.e. capsule i0=cq>>3 (and +16), j-quad jq=cq&7.
__global__ __launch_bounds__(1024, 4) void caps_stage(
    const float* __restrict__ u, const float* __restrict__ W,
    const float* __restrict__ onorm, float* __restrict__ part)
{
    __shared__ float Wq[2][4 * NCOL];   // 2 x 16 KB quarter tiles (4 k-rows)
    __shared__ float ub[2][BB * KK];    // 2 x 2 KB u slices
    __shared__ float logit_sh[BB * CC];
    __shared__ float c_sh[BB * CC];

    const int tid  = threadIdx.x;
    const int wave = tid >> 6;
    const int lane = tid & 63;
    const int bg = tid >> 7, cq = tid & 127;
    const int i0 = cq >> 3, jq = cq & 7;
    const int b0 = bg << 2, c0 = cq << 2;

    const int n0 = blockIdx.x * NPB;
    const int wl = (wave << 8) + (lane << 2);   // float offset: wave*256 + lane*4

    // prologue: quarter 0 of n0 (rows k=0..3) + u(n0)  [n0 even -> ub[0]]
    dma16(W + (size_t)(4 * n0) * 4096 + wl, &Wq[0][wl]);
    if (wave < 2)
        dma16(u + (size_t)((wave << 4) + (lane >> 2)) * (NN * KK) + n0 * KK + ((lane & 3) << 2),
              &ub[0][wl]);
    __syncthreads();   // drains prologue DMA

    float opart[2][4][4];
#pragma unroll
    for (int s = 0; s < 2; ++s)
#pragma unroll
        for (int bb = 0; bb < 4; ++bb)
#pragma unroll
            for (int m = 0; m < 4; ++m) opart[s][bb][m] = 0.f;

    for (int nn = 0; nn < NPB; ++nn) {
        const int n = n0 + nn;
        const float* ush = ub[n & 1];

        float accU[2][4][4];
#pragma unroll
        for (int s = 0; s < 2; ++s)
#pragma unroll
            for (int bb = 0; bb < 4; ++bb)
#pragma unroll
                for (int m = 0; m < 4; ++m) accU[s][bb][m] = 0.f;

#pragma unroll
        for (int q = 0; q < 4; ++q) {
            // prefetch next quarter into the OTHER buffer ((q+1)&1 — fixed
            // parity even when the address clamps at the global tail)
            {
                int Qn = 4 * n + q + 1;
                if (Qn > 4 * NN - 1) Qn = 4 * NN - 1;
                dma16(W + (size_t)Qn * 4096 + wl, &Wq[(q + 1) & 1][wl]);
            }
            if (q == 3) {
                const int nx = (n + 1 < NN) ? n + 1 : NN - 1;
                if (wave < 2)
                    dma16(u + (size_t)((wave << 4) + (lane >> 2)) * (NN * KK)
                            + nx * KK + ((lane & 3) << 2),
                          &ub[(n + 1) & 1][wl]);
            }

            // compute k = 4q..4q+3 from Wq[q&1] (LDS), u broadcast from LDS
            const float* Wsh = Wq[q & 1];
            float4 uu[4];
#pragma unroll
            for (int bb = 0; bb < 4; ++bb)
                uu[bb] = *(const float4*)&ush[(b0 + bb) * KK + (q << 2)];
#pragma unroll
            for (int kk = 0; kk < 4; ++kk) {
                const float4 w0 = *(const float4*)&Wsh[kk * NCOL + c0];
                const float4 w1 = *(const float4*)&Wsh[kk * NCOL + c0 + 512];
#pragma unroll
                for (int bb = 0; bb < 4; ++bb) {
                    const float uv = (kk == 0) ? uu[bb].x : (kk == 1) ? uu[bb].y
                                   : (kk == 2) ? uu[bb].z : uu[bb].w;
                    accU[0][bb][0] = fmaf(uv, w0.x, accU[0][bb][0]);
                    accU[0][bb][1] = fmaf(uv, w0.y, accU[0][bb][1]);
                    accU[0][bb][2] = fmaf(uv, w0.z, accU[0][bb][2]);
                    accU[0][bb][3] = fmaf(uv, w0.w, accU[0][bb][3]);
                    accU[1][bb][0] = fmaf(uv, w1.x, accU[1][bb][0]);
                    accU[1][bb][1] = fmaf(uv, w1.y, accU[1][bb][1]);
                    accU[1][bb][2] = fmaf(uv, w1.z, accU[1][bb][2]);
                    accU[1][bb][3] = fmaf(uv, w1.w, accU[1][bb][3]);
                }
            }
            if (q < 3) __syncthreads();  // done reading Wq[q&1]; drains prefetch
        }

        // ---- logits: dot with onorm, reduce over jq (lanes bits 0..2) ----
        float lp[2][4];
#pragma unroll
        for (int s = 0; s < 2; ++s)
#pragma unroll
            for (int bb = 0; bb < 4; ++bb) {
                const float4 on4 = *(const float4*)(
                    onorm + ((size_t)(b0 + bb) * CC + (i0 + s * 16)) * DD + (jq << 2));
                float p = accU[s][bb][0] * on4.x + accU[s][bb][1] * on4.y
                        + accU[s][bb][2] * on4.z + accU[s][bb][3] * on4.w;
                p += __shfl_xor(p, 1);
                p += __shfl_xor(p, 2);
                p += __shfl_xor(p, 4);
                lp[s][bb] = p;
            }
        if (jq == 0) {
#pragma unroll
            for (int s = 0; s < 2; ++s)
#pragma unroll
                for (int bb = 0; bb < 4; ++bb)
                    logit_sh[(b0 + bb) * CC + i0 + s * 16] = lp[s][bb];
        }
        __syncthreads();   // (B) logits ready; also drains q0(n+1)/u(n+1) DMA

        // ---- softmax over capsules: thread = (b = tid>>5, cap = tid&31) ----
        {
            const int b  = tid >> 5;
            const int ii = tid & 31;
            float l = logit_sh[b * CC + ii];
            float mx = l;
#pragma unroll
            for (int msk = 16; msk >= 1; msk >>= 1)
                mx = fmaxf(mx, __shfl_xor(mx, msk));
            const float e = __expf(l - mx);
            float sm = e;
#pragma unroll
            for (int msk = 16; msk >= 1; msk >>= 1)
                sm += __shfl_xor(sm, msk);
            c_sh[b * CC + ii] = e / sm;
        }
        __syncthreads();   // (C) c ready

        // ---- opart += c * U ----
#pragma unroll
        for (int s = 0; s < 2; ++s)
#pragma unroll
            for (int bb = 0; bb < 4; ++bb) {
                const float cc = c_sh[(b0 + bb) * CC + i0 + s * 16];
#pragma unroll
                for (int m = 0; m < 4; ++m)
                    opart[s][bb][m] = fmaf(cc, accU[s][bb][m], opart[s][bb][m]);
            }
    }

    // flush partials, coalesced float4 stores
    float* my = part + (size_t)blockIdx.x * OSZ;
#pragma unroll
    for (int s = 0; s < 2; ++s)
#pragma unroll
        for (int bb = 0; bb < 4; ++bb) {
            float4 v;
            v.x = opart[s][bb][0]; v.y = opart[s][bb][1];
            v.z = opart[s][bb][2]; v.w = opart[s][bb][3];
            *(float4*)&my[(b0 + bb) * NCOL + c0 + (s << 9)] = v;
        }
}

// Level-1 reduce: 256 partial images -> NSLICE slice images.
__global__ __launch_bounds__(256) void caps_reduce1(
    const float* __restrict__ part, float* __restrict__ ws2)
{
    const int gid   = blockIdx.x * 256 + threadIdx.x;     // 0..65535
    const int slice = gid >> 13;                          // 0..7
    const int q     = gid & 8191;                         // col-quad
    float4 acc = make_float4(0.f, 0.f, 0.f, 0.f);
    const float* p = part + ((size_t)slice * 32) * OSZ + (q << 2);
#pragma unroll 8
    for (int j = 0; j < 32; ++j) {
        const float4 v = *(const float4*)(p + (size_t)j * OSZ);
        acc.x += v.x; acc.y += v.y; acc.z += v.z; acc.w += v.w;
    }
    *(float4*)(ws2 + ((size_t)gid << 2)) = acc;
}

// Level-2 reduce + row op. mode 0: l2-normalize. mode 1: squash.
__global__ __launch_bounds__(256) void caps_reduce2(
    const float* __restrict__ ws2, float* __restrict__ dst, int mode)
{
    const int q = blockIdx.x * 256 + threadIdx.x;         // 0..8191
    float4 acc = make_float4(0.f, 0.f, 0.f, 0.f);
#pragma unroll
    for (int s = 0; s < NSLICE; ++s) {
        const float4 v = *(const float4*)(ws2 + ((size_t)s << 15) + (q << 2));
        acc.x += v.x; acc.y += v.y; acc.z += v.z; acc.w += v.w;
    }
    float s2 = acc.x * acc.x + acc.y * acc.y + acc.z * acc.z + acc.w * acc.w;
    s2 += __shfl_xor(s2, 1);
    s2 += __shfl_xor(s2, 2);
    s2 += __shfl_xor(s2, 4);
    float scale;
    if (mode == 0) {
        scale = rsqrtf(fmaxf(s2, 1e-12f));
    } else {
        scale = (s2 / (1.f + s2)) / sqrtf(s2 + 1e-7f);
    }
    float4 o;
    o.x = acc.x * scale; o.y = acc.y * scale;
    o.z = acc.z * scale; o.w = acc.w * scale;
    *(float4*)(dst + ((size_t)q << 2)) = o;
}

extern "C" void kernel_launch(void* const* d_in, const int* in_sizes, int n_in,
                              void* d_out, int out_size, void* d_ws, size_t ws_size,
                              hipStream_t stream)
{
    const float* u = (const float*)d_in[0];   // (32, 2048, 16)
    const float* W = (const float*)d_in[1];   // (2048, 16, 1024)
    float* out = (float*)d_out;               // (32, 32, 32)

    // ws layout: part (256*32768 fl = 32 MB) | ws2 (1 MB) | onorm (128 KB)
    float* part  = (float*)d_ws;
    float* ws2   = part + (size_t)256 * OSZ;
    float* onorm = ws2 + (size_t)NSLICE * OSZ;

    // onorm = 0 => logits 0 => softmax uniform 1/32 (exactly iteration 0)
    hipMemsetAsync(onorm, 0, (size_t)OSZ * sizeof(float), stream);

    for (int it = 0; it < 3; ++it) {
        caps_stage<<<NN / NPB, 1024, 0, stream>>>(u, W, onorm, part);
        caps_reduce1<<<256, 256, 0, stream>>>(part, ws2);
        if (it < 2)
            caps_reduce2<<<32, 256, 0, stream>>>(ws2, onorm, 0);  // l2-normalize
        else
            caps_reduce2<<<32, 256, 0, stream>>>(ws2, out, 1);    // squash -> d_out
    }
}

// Round 4
// 591.646 us; speedup vs baseline: 1.8651x; 1.8651x over previous
//
#include <hip/hip_runtime.h>
#include <math.h>
#include <stdint.h>

// Problem constants
#define BB   32     // batch
#define NN   2048   // input capsules
#define KK   16     // input dim
#define CC   32     // output capsules
#define DD   32     // capsule dim
#define NCOL 1024   // CC*DD
#define NPB  8      // n per block -> 256 blocks (1/CU)
#define WT   (KK * NCOL)          // 16384 floats = one 64 KB W tile
#define OSZ  (BB * NCOL)          // 32768 floats = one full o/partial image
#define NSLICE 8                  // reduce tree fan-in stage 1: 256 -> 8

// async global->LDS. Global addr is per-lane; LDS dest must be the
// WAVE-UNIFORM base — HW writes lane i's 16 B at base + 16*i.
__device__ __forceinline__ void dma16(const float* g, const float* l) {
    __builtin_amdgcn_global_load_lds(
        (const __attribute__((address_space(1))) void*)(uintptr_t)g,
        (__attribute__((address_space(3))) void*)(uintptr_t)l,
        16, 0, 0);
}

// One routing iteration, fused. Per n:
//   U[b,col] = sum_k u[b,n,k] * W[n,k,col]; logit[b,c] = <U, onorm>;
//   softmax over caps; opart += c*U.
// Round-3 lesson: compiler budgets 64 VGPR for 1024-thread blocks (max-occupancy
// default) and spilled the 64 accumulator floats -> 600 MB scratch traffic.
// amdgpu_waves_per_eu(4,4) pins 4 waves/EU (= our 1 block/CU) -> 128 VGPR budget.
// W is staged as FULL 64 KB tiles, double-buffered (140 KB LDS total, fits
// gfx950's 160 KB): 2 barriers per n, DMA issued a full iteration ahead.
__global__ __attribute__((amdgpu_flat_work_group_size(1024, 1024),
                          amdgpu_waves_per_eu(4, 4)))
void caps_stage(const float* __restrict__ u, const float* __restrict__ W,
                const float* __restrict__ onorm, float* __restrict__ part)
{
    __shared__ float Wt[2][WT];         // 2 x 64 KB W tiles
    __shared__ float ubuf[2][BB * KK];  // 2 x 2 KB u slices
    __shared__ float logit_sh[BB * CC];
    __shared__ float c_sh[BB * CC];

    const int tid  = threadIdx.x;
    const int wave = tid >> 6;
    const int lane = tid & 63;
    const int bg = tid >> 7, cq = tid & 127;
    const int i0 = cq >> 3, jq = cq & 7;
    const int b0 = bg << 2, c0 = cq << 2;
    const int n0 = blockIdx.x * NPB;

    const int woff = wave << 10;        // wave * 1024 floats (4 KB chunk base)
    const int loff = lane << 2;         // lane * 4 floats (16 B)

    // DMA one n's W tile (16 waves x 4 KB) + u slice (waves 0,1) into buf
    auto dma_tile = [&](int n, int buf) {
        const float* g = W + (size_t)n * WT + woff;
        const float* l = &Wt[buf][woff];           // wave-uniform LDS base
#pragma unroll
        for (int j = 0; j < 4; ++j)
            dma16(g + j * 256 + loff, l + j * 256);
        if (wave < 2) {
            // lane l: b = wave*16 + l/4, k = (l%4)*4; LDS float ofs = 16*l/4*... = 4*l
            dma16(u + (size_t)((wave << 4) + (lane >> 2)) * (NN * KK)
                    + n * KK + ((lane & 3) << 2),
                  &ubuf[buf][wave << 8]);          // wave-uniform base
        }
    };

    // prologue: tile(n0) -> buf 0 (drained by the syncthreads below)
    dma_tile(n0, 0);
    __syncthreads();

    float opart[2][4][4];
#pragma unroll
    for (int s = 0; s < 2; ++s)
#pragma unroll
        for (int bb = 0; bb < 4; ++bb)
#pragma unroll
            for (int m = 0; m < 4; ++m) opart[s][bb][m] = 0.f;

    for (int nn = 0; nn < NPB; ++nn) {
        const int n   = n0 + nn;
        const int cur = nn & 1;

        // prefetch next tile into the other buffer (safe: all threads passed
        // C(nn-1), so all reads of Wt[cur^1] from iter nn-1 are complete)
        {
            int np = n + 1;
            if (np >= NN) np = NN - 1;   // tail clamp (redundant load, harmless)
            dma_tile(np, cur ^ 1);
        }

        const float* Wsh = Wt[cur];
        const float* ush = ubuf[cur];

        float accU[2][4][4];
#pragma unroll
        for (int s = 0; s < 2; ++s)
#pragma unroll
            for (int bb = 0; bb < 4; ++bb)
#pragma unroll
                for (int m = 0; m < 4; ++m) accU[s][bb][m] = 0.f;

#pragma unroll
        for (int q = 0; q < 4; ++q) {
            float4 uu[4];
#pragma unroll
            for (int bb = 0; bb < 4; ++bb)
                uu[bb] = *(const float4*)&ush[(b0 + bb) * KK + (q << 2)];
#pragma unroll
            for (int kk = 0; kk < 4; ++kk) {
                const float4 w0 = *(const float4*)&Wsh[((q << 2) + kk) * NCOL + c0];
                const float4 w1 = *(const float4*)&Wsh[((q << 2) + kk) * NCOL + c0 + 512];
#pragma unroll
                for (int bb = 0; bb < 4; ++bb) {
                    const float uv = (kk == 0) ? uu[bb].x : (kk == 1) ? uu[bb].y
                                   : (kk == 2) ? uu[bb].z : uu[bb].w;
                    accU[0][bb][0] = fmaf(uv, w0.x, accU[0][bb][0]);
                    accU[0][bb][1] = fmaf(uv, w0.y, accU[0][bb][1]);
                    accU[0][bb][2] = fmaf(uv, w0.z, accU[0][bb][2]);
                    accU[0][bb][3] = fmaf(uv, w0.w, accU[0][bb][3]);
                    accU[1][bb][0] = fmaf(uv, w1.x, accU[1][bb][0]);
                    accU[1][bb][1] = fmaf(uv, w1.y, accU[1][bb][1]);
                    accU[1][bb][2] = fmaf(uv, w1.z, accU[1][bb][2]);
                    accU[1][bb][3] = fmaf(uv, w1.w, accU[1][bb][3]);
                }
            }
        }

        // ---- logits: dot with onorm, reduce over jq (lane bits 0..2) ----
        float lp[2][4];
#pragma unroll
        for (int s = 0; s < 2; ++s)
#pragma unroll
            for (int bb = 0; bb < 4; ++bb) {
                const float4 on4 = *(const float4*)(
                    onorm + ((size_t)(b0 + bb) * CC + (i0 + s * 16)) * DD + (jq << 2));
                float p = accU[s][bb][0] * on4.x + accU[s][bb][1] * on4.y
                        + accU[s][bb][2] * on4.z + accU[s][bb][3] * on4.w;
                p += __shfl_xor(p, 1);
                p += __shfl_xor(p, 2);
                p += __shfl_xor(p, 4);
                lp[s][bb] = p;
            }
        if (jq == 0) {
#pragma unroll
            for (int s = 0; s < 2; ++s)
#pragma unroll
                for (int bb = 0; bb < 4; ++bb)
                    logit_sh[(b0 + bb) * CC + i0 + s * 16] = lp[s][bb];
        }
        __syncthreads();   // (B) logits ready; drains this iter's prefetch DMA

        // ---- softmax over capsules: thread = (b = tid>>5, cap = tid&31) ----
        {
            const int b  = tid >> 5;
            const int ii = tid & 31;
            float l = logit_sh[b * CC + ii];
            float mx = l;
#pragma unroll
            for (int msk = 16; msk >= 1; msk >>= 1)
                mx = fmaxf(mx, __shfl_xor(mx, msk));
            const float e = __expf(l - mx);
            float sm = e;
#pragma unroll
            for (int msk = 16; msk >= 1; msk >>= 1)
                sm += __shfl_xor(sm, msk);
            c_sh[b * CC + ii] = e / sm;
        }
        __syncthreads();   // (C) c ready

        // ---- opart += c * U ----
#pragma unroll
        for (int s = 0; s < 2; ++s)
#pragma unroll
            for (int bb = 0; bb < 4; ++bb) {
                const float cc = c_sh[(b0 + bb) * CC + i0 + s * 16];
#pragma unroll
                for (int m = 0; m < 4; ++m)
                    opart[s][bb][m] = fmaf(cc, accU[s][bb][m], opart[s][bb][m]);
            }
    }

    // flush partials, coalesced float4 stores
    float* my = part + (size_t)blockIdx.x * OSZ;
#pragma unroll
    for (int s = 0; s < 2; ++s)
#pragma unroll
        for (int bb = 0; bb < 4; ++bb) {
            float4 v;
            v.x = opart[s][bb][0]; v.y = opart[s][bb][1];
            v.z = opart[s][bb][2]; v.w = opart[s][bb][3];
            *(float4*)&my[(b0 + bb) * NCOL + c0 + (s << 9)] = v;
        }
}

// Level-1 reduce: 256 partial images -> NSLICE slice images.
__global__ __launch_bounds__(256) void caps_reduce1(
    const float* __restrict__ part, float* __restrict__ ws2)
{
    const int gid   = blockIdx.x * 256 + threadIdx.x;     // 0..65535
    const int slice = gid >> 13;                          // 0..7
    const int q     = gid & 8191;                         // col-quad
    float4 acc = make_float4(0.f, 0.f, 0.f, 0.f);
    const float* p = part + ((size_t)slice * 32) * OSZ + (q << 2);
#pragma unroll 8
    for (int j = 0; j < 32; ++j) {
        const float4 v = *(const float4*)(p + (size_t)j * OSZ);
        acc.x += v.x; acc.y += v.y; acc.z += v.z; acc.w += v.w;
    }
    *(float4*)(ws2 + ((size_t)gid << 2)) = acc;
}

// Level-2 reduce + row op. mode 0: l2-normalize. mode 1: squash.
__global__ __launch_bounds__(256) void caps_reduce2(
    const float* __restrict__ ws2, float* __restrict__ dst, int mode)
{
    const int q = blockIdx.x * 256 + threadIdx.x;         // 0..8191
    float4 acc = make_float4(0.f, 0.f, 0.f, 0.f);
#pragma unroll
    for (int s = 0; s < NSLICE; ++s) {
        const float4 v = *(const float4*)(ws2 + ((size_t)s << 15) + (q << 2));
        acc.x += v.x; acc.y += v.y; acc.z += v.z; acc.w += v.w;
    }
    float s2 = acc.x * acc.x + acc.y * acc.y + acc.z * acc.z + acc.w * acc.w;
    s2 += __shfl_xor(s2, 1);
    s2 += __shfl_xor(s2, 2);
    s2 += __shfl_xor(s2, 4);
    float scale;
    if (mode == 0) {
        scale = rsqrtf(fmaxf(s2, 1e-12f));
    } else {
        scale = (s2 / (1.f + s2)) / sqrtf(s2 + 1e-7f);
    }
    float4 o;
    o.x = acc.x * scale; o.y = acc.y * scale;
    o.z = acc.z * scale; o.w = acc.w * scale;
    *(float4*)(dst + ((size_t)q << 2)) = o;
}

extern "C" void kernel_launch(void* const* d_in, const int* in_sizes, int n_in,
                              void* d_out, int out_size, void* d_ws, size_t ws_size,
                              hipStream_t stream)
{
    const float* u = (const float*)d_in[0];   // (32, 2048, 16)
    const float* W = (const float*)d_in[1];   // (2048, 16, 1024)
    float* out = (float*)d_out;               // (32, 32, 32)

    // ws layout: part (256*32768 fl = 32 MB) | ws2 (1 MB) | onorm (128 KB)
    float* part  = (float*)d_ws;
    float* ws2   = part + (size_t)256 * OSZ;
    float* onorm = ws2 + (size_t)NSLICE * OSZ;

    // onorm = 0 => logits 0 => softmax uniform 1/32 (exactly iteration 0)
    hipMemsetAsync(onorm, 0, (size_t)OSZ * sizeof(float), stream);

    for (int it = 0; it < 3; ++it) {
        caps_stage<<<NN / NPB, 1024, 0, stream>>>(u, W, onorm, part);
        caps_reduce1<<<256, 256, 0, stream>>>(part, ws2);
        if (it < 2)
            caps_reduce2<<<32, 256, 0, stream>>>(ws2, onorm, 0);  // l2-normalize
        else
            caps_reduce2<<<32, 256, 0, stream>>>(ws2, out, 1);    // squash -> d_out
    }
}

// Round 5
// 392.887 us; speedup vs baseline: 2.8086x; 1.5059x over previous
//
#include <hip/hip_runtime.h>
#include <math.h>
#include <stdint.h>

// Problem constants
#define BB   32     // batch
#define HB   16     // batch per block (b-split: 2 blocks per n-group)
#define NN   2048   // input capsules
#define KK   16     // input dim
#define CC   32     // output capsules
#define DD   32     // capsule dim
#define NCOL 1024   // CC*DD
#define NPB  8      // n per block -> 256 n-groups x 2 b-halves = 512 blocks (2/CU)
#define WT   (KK * NCOL)          // 16384 floats = one 64 KB W tile
#define OSZ  (BB * NCOL)          // 32768 floats = one full o/partial image
#define NSLICE 8                  // reduce tree fan-in stage 1: 256 -> 8

// async global->LDS. Global addr is per-lane; LDS dest must be the
// WAVE-UNIFORM base — HW writes lane i's 16 B at base + 16*i.
__device__ __forceinline__ void dma16(const float* g, const float* l) {
    __builtin_amdgcn_global_load_lds(
        (const __attribute__((address_space(1))) void*)(uintptr_t)g,
        (__attribute__((address_space(3))) void*)(uintptr_t)l,
        16, 0, 0);
}

// One routing iteration, fused. Per n:
//   U[b,col] = sum_k u[b,n,k] * W[n,k,col]; logit[b,c] = <U, onorm>;
//   softmax over caps; opart += c*U.
// R3/R4 lesson: the compiler pins 1024-thread blocks at 64 VGPR and neither
// __launch_bounds__(,4) nor amdgpu_waves_per_eu raises it -> accU+opart (64
// floats with 32 b/block) spilled ~300 MB/stage to scratch. Fix: DESIGN for
// 64 VGPR — split batch across 2 blocks (16 b each). Per-thread accumulators
// halve to 16+16 floats -> no spill. Softmax couples capsules, not batches,
// so the split is fusion-safe. 512 blocks = 2 blocks/CU: the co-resident
// block covers the single-buffer DMA drain at barriers (double-buffer's LDS
// would forbid 2 blocks/CU). LDS 76 KB: Wt 64 + u(all 8 n, [n][k][b]) 8 + 4.
__global__ __launch_bounds__(1024)
void caps_stage(const float* __restrict__ u, const float* __restrict__ W,
                const float* __restrict__ onorm, float* __restrict__ part)
{
    __shared__ float Wt[WT];                 // 64 KB single-buffer W tile
    __shared__ float ush[NPB * KK * HB];     // 8 KB: [n][k][b] all 8 n's
    __shared__ float logit_sh[HB * CC];      // 2 KB
    __shared__ float c_sh[HB * CC];          // 2 KB

    const int tid  = threadIdx.x;
    const int wave = tid >> 6;
    const int lane = tid & 63;
    const int bg = tid >> 8;          // 0..3 -> 4 local b's each
    const int cq = tid & 255;         // col-quad 0..255
    const int i0 = cq >> 3;           // capsule 0..31
    const int jq = cq & 7;            // d-quad
    const int b0 = bg << 2;           // local b base
    const int c0 = cq << 2;           // col base

    const int ngrp  = blockIdx.x >> 1;
    const int bhalf = blockIdx.x & 1;
    const int n0    = ngrp * NPB;
    const int bbase = bhalf * HB;     // global b offset

    const int woff = wave << 10;      // wave * 1024 floats (4 KB chunk)
    const int loff = lane << 2;       // lane * 4 floats

    // DMA one n's 64 KB W tile: 16 waves x 4 x 16B/lane
    auto dma_tile = [&](int n) {
        const float* g = W + (size_t)n * WT + woff + loff;
        const float* l = &Wt[woff];   // wave-uniform LDS base
#pragma unroll
        for (int j = 0; j < 4; ++j)
            dma16(g + j * 256, l + j * 256);
    };

    // prologue: W tile n0 + ALL u for this block (8 KB, transposed [n][k][b])
    dma_tile(n0);
    for (int idx = tid; idx < NPB * KK * HB; idx += 1024) {
        const int n = idx >> 8, rem = idx & 255, k = rem >> 4, b = rem & 15;
        ush[idx] = u[(size_t)(bbase + b) * (NN * KK) + (size_t)(n0 + n) * KK + k];
    }
    __syncthreads();   // drains prologue DMA + ush writes

    float opart[4][4];
#pragma unroll
    for (int bb = 0; bb < 4; ++bb)
#pragma unroll
        for (int m = 0; m < 4; ++m) opart[bb][m] = 0.f;

    for (int nn = 0; nn < NPB; ++nn) {
        // Wt holds tile nn (drained at barrier C of prev iter / prologue)
        const float* un = &ush[nn << 8];

        float accU[4][4];
#pragma unroll
        for (int bb = 0; bb < 4; ++bb)
#pragma unroll
            for (int m = 0; m < 4; ++m) accU[bb][m] = 0.f;

#pragma unroll
        for (int k = 0; k < KK; ++k) {
            const float4 w  = *(const float4*)&Wt[k * NCOL + c0];
            const float4 ub = *(const float4*)&un[(k << 4) + b0];  // u[b0..b0+3][k]
            accU[0][0] = fmaf(ub.x, w.x, accU[0][0]);
            accU[0][1] = fmaf(ub.x, w.y, accU[0][1]);
            accU[0][2] = fmaf(ub.x, w.z, accU[0][2]);
            accU[0][3] = fmaf(ub.x, w.w, accU[0][3]);
            accU[1][0] = fmaf(ub.y, w.x, accU[1][0]);
            accU[1][1] = fmaf(ub.y, w.y, accU[1][1]);
            accU[1][2] = fmaf(ub.y, w.z, accU[1][2]);
            accU[1][3] = fmaf(ub.y, w.w, accU[1][3]);
            accU[2][0] = fmaf(ub.z, w.x, accU[2][0]);
            accU[2][1] = fmaf(ub.z, w.y, accU[2][1]);
            accU[2][2] = fmaf(ub.z, w.z, accU[2][2]);
            accU[2][3] = fmaf(ub.z, w.w, accU[2][3]);
            accU[3][0] = fmaf(ub.w, w.x, accU[3][0]);
            accU[3][1] = fmaf(ub.w, w.y, accU[3][1]);
            accU[3][2] = fmaf(ub.w, w.z, accU[3][2]);
            accU[3][3] = fmaf(ub.w, w.w, accU[3][3]);
        }

        // ---- logits: dot with onorm (L2-resident), reduce over jq lanes ----
        float lp[4];
#pragma unroll
        for (int bb = 0; bb < 4; ++bb) {
            const float4 on4 = *(const float4*)(
                onorm + ((size_t)(bbase + b0 + bb) * CC + i0) * DD + (jq << 2));
            float p = accU[bb][0] * on4.x + accU[bb][1] * on4.y
                    + accU[bb][2] * on4.z + accU[bb][3] * on4.w;
            p += __shfl_xor(p, 1);
            p += __shfl_xor(p, 2);
            p += __shfl_xor(p, 4);
            lp[bb] = p;
        }
        if (jq == 0) {
#pragma unroll
            for (int bb = 0; bb < 4; ++bb)
                logit_sh[(b0 + bb) * CC + i0] = lp[bb];
        }
        __syncthreads();   // (B) logits ready AND all Wt reads done

        // prefetch next W tile into the (single) buffer — legal after B
        {
            int np = n0 + nn + 1;
            if (np >= NN) np = NN - 1;   // tail clamp, redundant load harmless
            dma_tile(np);
        }

        // ---- softmax over capsules: 512 threads, (b = tid>>5, cap = tid&31) ----
        if (tid < HB * CC) {
            const int b  = tid >> 5;
            const int ii = tid & 31;
            float l = logit_sh[b * CC + ii];
            float mx = l;
#pragma unroll
            for (int msk = 16; msk >= 1; msk >>= 1)
                mx = fmaxf(mx, __shfl_xor(mx, msk));
            const float e = __expf(l - mx);
            float sm = e;
#pragma unroll
            for (int msk = 16; msk >= 1; msk >>= 1)
                sm += __shfl_xor(sm, msk);
            c_sh[b * CC + ii] = e / sm;
        }
        __syncthreads();   // (C) c ready; drains the tile-(nn+1) DMA

        // ---- opart += c * U ----
#pragma unroll
        for (int bb = 0; bb < 4; ++bb) {
            const float cc = c_sh[(b0 + bb) * CC + i0];
#pragma unroll
            for (int m = 0; m < 4; ++m)
                opart[bb][m] = fmaf(cc, accU[bb][m], opart[bb][m]);
        }
    }

    // flush partials, coalesced float4 stores (this block's 16-b half)
    float* my = part + (size_t)ngrp * OSZ + (size_t)bbase * NCOL;
#pragma unroll
    for (int bb = 0; bb < 4; ++bb) {
        float4 v;
        v.x = opart[bb][0]; v.y = opart[bb][1];
        v.z = opart[bb][2]; v.w = opart[bb][3];
        *(float4*)&my[(b0 + bb) * NCOL + c0] = v;
    }
}

// Level-1 reduce: 256 partial images -> NSLICE slice images.
__global__ __launch_bounds__(256) void caps_reduce1(
    const float* __restrict__ part, float* __restrict__ ws2)
{
    const int gid   = blockIdx.x * 256 + threadIdx.x;     // 0..65535
    const int slice = gid >> 13;                          // 0..7
    const int q     = gid & 8191;                         // col-quad
    float4 acc = make_float4(0.f, 0.f, 0.f, 0.f);
    const float* p = part + ((size_t)slice * 32) * OSZ + (q << 2);
#pragma unroll 8
    for (int j = 0; j < 32; ++j) {
        const float4 v = *(const float4*)(p + (size_t)j * OSZ);
        acc.x += v.x; acc.y += v.y; acc.z += v.z; acc.w += v.w;
    }
    *(float4*)(ws2 + ((size_t)gid << 2)) = acc;
}

// Level-2 reduce + row op. mode 0: l2-normalize. mode 1: squash.
__global__ __launch_bounds__(256) void caps_reduce2(
    const float* __restrict__ ws2, float* __restrict__ dst, int mode)
{
    const int q = blockIdx.x * 256 + threadIdx.x;         // 0..8191
    float4 acc = make_float4(0.f, 0.f, 0.f, 0.f);
#pragma unroll
    for (int s = 0; s < NSLICE; ++s) {
        const float4 v = *(const float4*)(ws2 + ((size_t)s << 15) + (q << 2));
        acc.x += v.x; acc.y += v.y; acc.z += v.z; acc.w += v.w;
    }
    float s2 = acc.x * acc.x + acc.y * acc.y + acc.z * acc.z + acc.w * acc.w;
    s2 += __shfl_xor(s2, 1);
    s2 += __shfl_xor(s2, 2);
    s2 += __shfl_xor(s2, 4);
    float scale;
    if (mode == 0) {
        scale = rsqrtf(fmaxf(s2, 1e-12f));
    } else {
        scale = (s2 / (1.f + s2)) / sqrtf(s2 + 1e-7f);
    }
    float4 o;
    o.x = acc.x * scale; o.y = acc.y * scale;
    o.z = acc.z * scale; o.w = acc.w * scale;
    *(float4*)(dst + ((size_t)q << 2)) = o;
}

extern "C" void kernel_launch(void* const* d_in, const int* in_sizes, int n_in,
                              void* d_out, int out_size, void* d_ws, size_t ws_size,
                              hipStream_t stream)
{
    const float* u = (const float*)d_in[0];   // (32, 2048, 16)
    const float* W = (const float*)d_in[1];   // (2048, 16, 1024)
    float* out = (float*)d_out;               // (32, 32, 32)

    // ws layout: part (256*32768 fl = 32 MB) | ws2 (1 MB) | onorm (128 KB)
    float* part  = (float*)d_ws;
    float* ws2   = part + (size_t)256 * OSZ;
    float* onorm = ws2 + (size_t)NSLICE * OSZ;

    // onorm = 0 => logits 0 => softmax uniform 1/32 (exactly iteration 0)
    hipMemsetAsync(onorm, 0, (size_t)OSZ * sizeof(float), stream);

    for (int it = 0; it < 3; ++it) {
        caps_stage<<<2 * (NN / NPB), 1024, 0, stream>>>(u, W, onorm, part);
        caps_reduce1<<<256, 256, 0, stream>>>(part, ws2);
        if (it < 2)
            caps_reduce2<<<32, 256, 0, stream>>>(ws2, onorm, 0);  // l2-normalize
        else
            caps_reduce2<<<32, 256, 0, stream>>>(ws2, out, 1);    // squash -> d_out
    }
}